// Round 5
// baseline (147.305 us; speedup 1.0000x reference)
//
#include <hip/hip_runtime.h>

// LieSE3: per row [x, y, p_yaw] -> 4x4 SE(3) matrix with z-only rotation.
//
// Closed form (w = 0.1*p, ts = w^2, th = |w|):
//   A  = sin(th)/(th+eps);  Bc = (1-cos th)/(ts+eps);  C = (1-A)/(ts+eps)
//   R00 = R11 = 1 - Bc*ts;  R10 = A*w = -R01
//   V00 = V11 = 1 - C*ts;   V10 = Bw = Bc*w
//   t0 = V00*x - Bw*y;  t1 = Bw*x + V00*y;  rows 2,3 = [0,0,1,0],[0,0,0,1]
//
// R4/R5 changes (input path + store path only; compute unchanged):
//  - Input staged via fully-coalesced float4 loads (192/block) into LDS;
//    per-thread x/y/p read from LDS at stride 3 (coprime with 32 banks ->
//    2 lanes/bank = conflict-free, which is free on gfx950).
//  - Output stores nontemporal (no L2 allocate): d_out is a 128 MB
//    write-once stream; keeping it out of L2 stops it evicting the input.
//    R5 fix: __builtin_nontemporal_store needs a clang native vector type,
//    not HIP's float4 struct -> use ext_vector_type(4).

#define ROTATION_SCALE 0.1f
#define EPS_F 1e-5f

typedef float nfloat4 __attribute__((ext_vector_type(4)));

__global__ __launch_bounds__(256) void lie_se3_kernel(
    const float4* __restrict__ uv4, float4* __restrict__ out,
    int B, int n4in) {
  __shared__ float sin_buf[768];   // 256 matrices x 3 floats (3 KB)
  __shared__ float4 sout[1024];    // 256 matrices x 4 rows  (16 KB)

  int tid = threadIdx.x;
  int blk = blockIdx.x;

  // ---- stage input: 192 coalesced float4s per block ----
  if (tid < 192) {
    int g4 = blk * 192 + tid;
    float4 v = (g4 < n4in) ? uv4[g4] : make_float4(0.f, 0.f, 0.f, 0.f);
    ((float4*)sin_buf)[tid] = v;
  }
  __syncthreads();

  float x = sin_buf[3 * tid + 0];
  float y = sin_buf[3 * tid + 1];
  float p = sin_buf[3 * tid + 2];

  float w = p * ROTATION_SCALE;
  float ts = w * w;
  float th = fabsf(w);
  float s = __sinf(th);
  float c = __cosf(th);
  float A  = s / (th + EPS_F);
  float Bc = (1.0f - c) / (ts + EPS_F);
  float C  = (1.0f - A) / (ts + EPS_F);

  float R00 = 1.0f - Bc * ts;  // == R11
  float Aw  = A * w;           // R10 = Aw, R01 = -Aw
  float V00 = 1.0f - C * ts;   // == V11
  float Bw  = Bc * w;          // V10 = Bw, V01 = -Bw
  float t0 = V00 * x - Bw * y;
  float t1 = Bw * x + V00 * y;

  sout[4 * tid + 0] = make_float4(R00, -Aw, 0.0f, t0);
  sout[4 * tid + 1] = make_float4(Aw, R00, 0.0f, t1);
  sout[4 * tid + 2] = make_float4(0.0f, 0.0f, 1.0f, 0.0f);
  sout[4 * tid + 3] = make_float4(0.0f, 0.0f, 0.0f, 1.0f);
  __syncthreads();

  // ---- coalesced nontemporal store phase ----
  long long base = (long long)blk * 1024;
  long long limit = 4LL * B;
  nfloat4* outN = (nfloat4*)out;
  const nfloat4* soutN = (const nfloat4*)sout;
  #pragma unroll
  for (int k = 0; k < 4; ++k) {
    int idx = tid + k * 256;
    long long g = base + idx;
    if (g < limit) {
      nfloat4 v = soutN[idx];
      __builtin_nontemporal_store(v, &outN[g]);
    }
  }
}

extern "C" void kernel_launch(void* const* d_in, const int* in_sizes, int n_in,
                              void* d_out, int out_size, void* d_ws, size_t ws_size,
                              hipStream_t stream) {
  const float4* uv4 = (const float4*)d_in[0];
  float4* out = (float4*)d_out;
  int B = in_sizes[0] / 3;        // 2,000,000
  int n4in = in_sizes[0] / 4;     // 1,500,000 float4s (6M floats, /4 exact)
  int block = 256;
  int grid = (B + block - 1) / block;  // one thread per matrix
  lie_se3_kernel<<<grid, block, 0, stream>>>(uv4, out, B, n4in);
}

// Round 6
// 144.942 us; speedup vs baseline: 1.0163x; 1.0163x over previous
//
#include <hip/hip_runtime.h>

// LieSE3: per row [x, y, p_yaw] -> 4x4 SE(3) matrix with z-only rotation.
//
// Closed form (w = 0.1*p, ts = w^2, th = |w|):
//   A  = sin(th)/(th+eps);  Bc = (1-cos th)/(ts+eps);  C = (1-A)/(ts+eps)
//   R00 = R11 = 1 - Bc*ts;  R10 = A*w = -R01
//   V00 = V11 = 1 - C*ts;   V10 = Bw = Bc*w
//   t0 = V00*x - Bw*y;  t1 = Bw*x + V00*y;  rows 2,3 = [0,0,1,0],[0,0,0,1]
//
// R6: revert R5's nontemporal stores (regressed 140->147: nt bypasses L2
// allocate, forcing the full 128 MB to land in HBM before store retirement;
// plain stores leave up to ~32 MB dirty in L2 at kernel end — free drain
// overlap). Keep R4's float4-coalesced input staging:
//  - 192 float4 loads/block into LDS; per-thread x/y/p read at stride 3
//    (2 lanes/bank = free on gfx950) replaces 3 stride-12 scalar loads.
//  - Output staged in LDS, store phase fully contiguous float4 per lane.

#define ROTATION_SCALE 0.1f
#define EPS_F 1e-5f

__global__ __launch_bounds__(256) void lie_se3_kernel(
    const float4* __restrict__ uv4, float4* __restrict__ out,
    int B, int n4in) {
  __shared__ float sin_buf[768];   // 256 matrices x 3 floats (3 KB)
  __shared__ float4 sout[1024];    // 256 matrices x 4 rows  (16 KB)

  int tid = threadIdx.x;
  int blk = blockIdx.x;

  // ---- stage input: 192 coalesced float4s per block ----
  if (tid < 192) {
    int g4 = blk * 192 + tid;
    float4 v = (g4 < n4in) ? uv4[g4] : make_float4(0.f, 0.f, 0.f, 0.f);
    ((float4*)sin_buf)[tid] = v;
  }
  __syncthreads();

  float x = sin_buf[3 * tid + 0];
  float y = sin_buf[3 * tid + 1];
  float p = sin_buf[3 * tid + 2];

  float w = p * ROTATION_SCALE;
  float ts = w * w;
  float th = fabsf(w);
  float s = __sinf(th);
  float c = __cosf(th);
  float A  = s / (th + EPS_F);
  float Bc = (1.0f - c) / (ts + EPS_F);
  float C  = (1.0f - A) / (ts + EPS_F);

  float R00 = 1.0f - Bc * ts;  // == R11
  float Aw  = A * w;           // R10 = Aw, R01 = -Aw
  float V00 = 1.0f - C * ts;   // == V11
  float Bw  = Bc * w;          // V10 = Bw, V01 = -Bw
  float t0 = V00 * x - Bw * y;
  float t1 = Bw * x + V00 * y;

  sout[4 * tid + 0] = make_float4(R00, -Aw, 0.0f, t0);
  sout[4 * tid + 1] = make_float4(Aw, R00, 0.0f, t1);
  sout[4 * tid + 2] = make_float4(0.0f, 0.0f, 1.0f, 0.0f);
  sout[4 * tid + 3] = make_float4(0.0f, 0.0f, 0.0f, 1.0f);
  __syncthreads();

  // ---- coalesced store phase (plain stores; L2 absorbs tail) ----
  long long base = (long long)blk * 1024;
  long long limit = 4LL * B;
  #pragma unroll
  for (int k = 0; k < 4; ++k) {
    int idx = tid + k * 256;
    long long g = base + idx;
    if (g < limit) out[g] = sout[idx];
  }
}

extern "C" void kernel_launch(void* const* d_in, const int* in_sizes, int n_in,
                              void* d_out, int out_size, void* d_ws, size_t ws_size,
                              hipStream_t stream) {
  const float4* uv4 = (const float4*)d_in[0];
  float4* out = (float4*)d_out;
  int B = in_sizes[0] / 3;        // 2,000,000
  int n4in = in_sizes[0] / 4;     // 1,500,000 float4s (6M floats, /4 exact)
  int block = 256;
  int grid = (B + block - 1) / block;  // one thread per matrix
  lie_se3_kernel<<<grid, block, 0, stream>>>(uv4, out, B, n4in);
}

// Round 7
// 143.577 us; speedup vs baseline: 1.0260x; 1.0095x over previous
//
#include <hip/hip_runtime.h>

// LieSE3: per row [x, y, p_yaw] -> 4x4 SE(3) matrix with z-only rotation.
//
// Closed form (w = 0.1*p, ts = w^2, th = |w|):
//   A  = sin(th)/(th+eps);  Bc = (1-cos th)/(ts+eps);  C = (1-A)/(ts+eps)
//   R00 = R11 = 1 - Bc*ts;  R10 = A*w = -R01
//   V00 = V11 = 1 - C*ts;   V10 = Bw = Bc*w
//   t0 = V00*x - Bw*y;  t1 = Bw*x + V00*y;  rows 2,3 = [0,0,1,0],[0,0,0,1]
//
// R7: slim the output exchange. Only 4 scalars/matrix (R00, Aw, t0, t1)
// are non-constant -> exchange exactly those through 4 KB of LDS (was a
// 16 KB float4 round-trip), ONE barrier (was two). Store phase: thread
// handles float4 indices tid+256k; since 256%4==0 its row type r=tid&3 is
// fixed -> rows 2/3 (HALF the 128 MB output) are pure immediates with no
// data dependency (issue while input loads are in flight). LDS read in
// store phase is 4-lane broadcast, 2-way bank alias = free. Stores stay
// perfectly wave-contiguous.

#define ROTATION_SCALE 0.1f
#define EPS_F 1e-5f

__global__ __launch_bounds__(256) void lie_se3_kernel(
    const float4* __restrict__ uv4, float4* __restrict__ out,
    int B, int n4in) {
  __shared__ float sin_buf[768];   // 256 matrices x 3 floats (3 KB)
  __shared__ float4 s4[256];       // (R00, Aw, t0, t1) per matrix (4 KB)

  int tid = threadIdx.x;
  int blk = blockIdx.x;

  // ---- stage input: 192 coalesced float4s per block ----
  if (tid < 192) {
    int g4 = blk * 192 + tid;
    float4 v = (g4 < n4in) ? uv4[g4] : make_float4(0.f, 0.f, 0.f, 0.f);
    ((float4*)sin_buf)[tid] = v;
  }
  __syncthreads();

  float x = sin_buf[3 * tid + 0];
  float y = sin_buf[3 * tid + 1];
  float p = sin_buf[3 * tid + 2];

  float w = p * ROTATION_SCALE;
  float ts = w * w;
  float th = fabsf(w);
  float s = __sinf(th);
  float c = __cosf(th);
  float A  = s / (th + EPS_F);
  float Bc = (1.0f - c) / (ts + EPS_F);
  float C  = (1.0f - A) / (ts + EPS_F);

  float R00 = 1.0f - Bc * ts;  // == R11
  float Aw  = A * w;           // R10 = Aw, R01 = -Aw
  float V00 = 1.0f - C * ts;   // == V11
  float Bw  = Bc * w;          // V10 = Bw, V01 = -Bw
  float t0 = V00 * x - Bw * y;
  float t1 = Bw * x + V00 * y;

  s4[tid] = make_float4(R00, Aw, t0, t1);
  __syncthreads();

  // ---- store phase: float4 index j = tid + 256k, matrix j>>2, row j&3 ----
  int r = tid & 3;              // fixed per thread (256 % 4 == 0)
  int mbase = tid >> 2;         // local matrix for k=0
  long long base = (long long)blk * 1024;
  long long limit = 4LL * B;
  #pragma unroll
  for (int k = 0; k < 4; ++k) {
    long long g = base + tid + 256 * k;
    if (g < limit) {
      float4 q = s4[mbase + 64 * k];   // broadcast read (4 lanes/addr)
      float4 v;
      v.x = (r == 0) ? q.x : ((r == 1) ? q.y : 0.0f);   // R00 / Aw / 0
      v.y = (r == 0) ? -q.y : ((r == 1) ? q.x : 0.0f);  // -Aw / R00 / 0
      v.z = (r == 2) ? 1.0f : 0.0f;
      v.w = (r == 0) ? q.z : ((r == 1) ? q.w : ((r == 3) ? 1.0f : 0.0f));
      out[g] = v;
    }
  }
}

extern "C" void kernel_launch(void* const* d_in, const int* in_sizes, int n_in,
                              void* d_out, int out_size, void* d_ws, size_t ws_size,
                              hipStream_t stream) {
  const float4* uv4 = (const float4*)d_in[0];
  float4* out = (float4*)d_out;
  int B = in_sizes[0] / 3;        // 2,000,000
  int n4in = in_sizes[0] / 4;     // 1,500,000 float4s
  int block = 256;
  int grid = (B + block - 1) / block;  // one thread per matrix
  lie_se3_kernel<<<grid, block, 0, stream>>>(uv4, out, B, n4in);
}